// Round 3
// baseline (888.469 us; speedup 1.0000x reference)
//
#include <hip/hip_runtime.h>
#include <stdint.h>
#include <stddef.h>

#define H_DIM 512
#define M_DIM 4096
#define TOPK  64
#define BAND_CAP 128
#define DEC_CAP 96
#define NBINS 2048

typedef __attribute__((ext_vector_type(8))) short bf16x8;
typedef __attribute__((ext_vector_type(4))) float floatx4;
typedef __attribute__((ext_vector_type(8))) unsigned short ushort8;

static __device__ __forceinline__ unsigned short f2bf(float f) {
    union { float ff; unsigned int i; } v; v.ff = f;
    unsigned int u = v.i;
    u += 0x7FFFu + ((u >> 16) & 1u);   // RNE
    return (unsigned short)(u >> 16);
}

static __device__ __forceinline__ void gload16(const void* g, void* l) {
    __builtin_amdgcn_global_load_lds(
        (const __attribute__((address_space(1))) unsigned int*)g,
        (__attribute__((address_space(3))) unsigned int*)l, 16, 0, 0);
}

// ---- prep: Xbf[n*H+h] = bf16(X - bpre)  (bit-identical f2bf to inline path)
__global__ void sae_conv_x(const float* __restrict__ X, const float* __restrict__ bpre,
                           unsigned short* __restrict__ Xbf) {
    int g = (blockIdx.x * 256 + threadIdx.x) * 8;
    int h = g & (H_DIM - 1);
    float4 a0 = *(const float4*)(X + g);
    float4 a1 = *(const float4*)(X + g + 4);
    float4 p0 = *(const float4*)(bpre + h);
    float4 p1 = *(const float4*)(bpre + h + 4);
    ushort8 o;
    o[0] = f2bf(a0.x - p0.x); o[1] = f2bf(a0.y - p0.y);
    o[2] = f2bf(a0.z - p0.z); o[3] = f2bf(a0.w - p0.w);
    o[4] = f2bf(a1.x - p1.x); o[5] = f2bf(a1.y - p1.y);
    o[6] = f2bf(a1.z - p1.z); o[7] = f2bf(a1.w - p1.w);
    *(ushort8*)(Xbf + g) = o;
}

// ---- prep: Encbf = bf16(Enc) elementwise
__global__ void sae_conv_enc(const float* __restrict__ Enc, unsigned short* __restrict__ Eb) {
    int g = (blockIdx.x * 256 + threadIdx.x) * 8;
    float4 b0 = *(const float4*)(Enc + g);
    float4 b1 = *(const float4*)(Enc + g + 4);
    ushort8 o;
    o[0] = f2bf(b0.x); o[1] = f2bf(b0.y); o[2] = f2bf(b0.z); o[3] = f2bf(b0.w);
    o[4] = f2bf(b1.x); o[5] = f2bf(b1.y); o[6] = f2bf(b1.z); o[7] = f2bf(b1.w);
    *(ushort8*)(Eb + g) = o;
}

// ---- prep: decTb[m*H + h] = bf16(dec[h*M + m])  via LDS tile transpose
__global__ void sae_conv_decT(const float* __restrict__ dec, unsigned short* __restrict__ decTb) {
    __shared__ float tile[64][65];
    const int m0 = blockIdx.x * 64;
    const int h0 = blockIdx.y * 64;
    const int tid = threadIdx.x;
#pragma unroll
    for (int it = 0; it < 16; ++it) {
        int r = it * 4 + (tid >> 6);      // h-local
        int c = tid & 63;                  // m-local (coalesced)
        tile[r][c] = dec[(size_t)(h0 + r) * M_DIM + m0 + c];
    }
    __syncthreads();
    const int ml = tid >> 2;
    const int q  = tid & 3;
    ushort8 o0, o1;
#pragma unroll
    for (int e = 0; e < 8; ++e) o0[e] = f2bf(tile[q * 16 + e][ml]);
#pragma unroll
    for (int e = 0; e < 8; ++e) o1[e] = f2bf(tile[q * 16 + 8 + e][ml]);
    unsigned short* out = decTb + (size_t)(m0 + ml) * H_DIM + h0 + q * 16;
    *(ushort8*)(out)     = o0;
    *(ushort8*)(out + 8) = o1;
}

// ---- K1 fast path: m97-structure BK=64 GEMM from precomputed bf16 arrays.
// K-chunk order (0,32,64,...) identical to the BK=32 path -> z bit-identical.
__launch_bounds__(256, 2)
__global__ void sae_encode_gemm64(const unsigned short* __restrict__ Xbf,   // [N,H] bf16
                                  const unsigned short* __restrict__ Encbf, // [M,H] bf16
                                  const float* __restrict__ benc,
                                  float* __restrict__ zbase)
{
    __shared__ unsigned short lA[128 * 64];   // 16 KB
    __shared__ unsigned short lB[128 * 64];   // 16 KB
    const int tid  = threadIdx.x;
    const int lane = tid & 63;
    const int wave = tid >> 6;
    const int wx = wave & 1, wy = wave >> 1;
    const int mBase = blockIdx.x * 128;
    const int nBase = blockIdx.y * 128;

    floatx4 acc[4][4];
#pragma unroll
    for (int i = 0; i < 4; ++i)
#pragma unroll
        for (int j = 0; j < 4; ++j) acc[i][j] = (floatx4){0.f, 0.f, 0.f, 0.f};

    // staging map: instr j stages rows wave*32 + j*8 + (lane>>3), cols (lane&7)*8
    // LDS elem offset = wave*2048 + j*512 + lane*8 (linear row*64+col)
    const int gRow = wave * 32 + (lane >> 3);
    const int gCol = (lane & 7) * 8;
    const int lOff = wave * 2048 + lane * 8;
    const unsigned short* gA = Xbf  + (size_t)(nBase + gRow) * H_DIM + gCol;
    const unsigned short* gB = Encbf + (size_t)(mBase + gRow) * H_DIM + gCol;

    const int quad = lane >> 4;
    const int l15  = lane & 15;

    for (int kt = 0; kt < H_DIM / 64; ++kt) {
        const int k0 = kt * 64;
        __syncthreads();
#pragma unroll
        for (int j = 0; j < 4; ++j)
            gload16(gA + (size_t)(j * 8) * H_DIM + k0, &lA[lOff + j * 512]);
#pragma unroll
        for (int j = 0; j < 4; ++j)
            gload16(gB + (size_t)(j * 8) * H_DIM + k0, &lB[lOff + j * 512]);
        __syncthreads();
#pragma unroll
        for (int kk = 0; kk < 2; ++kk) {
            bf16x8 af[4], bfr[4];
#pragma unroll
            for (int i = 0; i < 4; ++i)
                af[i] = *(const bf16x8*)&lA[(wy * 64 + i * 16 + l15) * 64 + kk * 32 + quad * 8];
#pragma unroll
            for (int j = 0; j < 4; ++j)
                bfr[j] = *(const bf16x8*)&lB[(wx * 64 + j * 16 + l15) * 64 + kk * 32 + quad * 8];
#pragma unroll
            for (int i = 0; i < 4; ++i)
#pragma unroll
                for (int j = 0; j < 4; ++j)
                    acc[i][j] = __builtin_amdgcn_mfma_f32_16x16x32_bf16(af[i], bfr[j], acc[i][j], 0, 0, 0);
        }
    }

#pragma unroll
    for (int i = 0; i < 4; ++i) {
        int nLoc = nBase + wy * 64 + i * 16 + quad * 4;
#pragma unroll
        for (int j = 0; j < 4; ++j) {
            int m = mBase + wx * 64 + j * 16 + l15;
            float bc = benc[m];
#pragma unroll
            for (int r = 0; r < 4; ++r) {
                float v = acc[i][j][r] + bc;
                v = v > 0.f ? v : 0.f;
                zbase[(size_t)(nLoc + r) * M_DIM + m] = v;
            }
        }
    }
}

// ---- K1 fallback (small ws): original BK=32 kernel with inline f2bf
template<int BBF>
__launch_bounds__(256, 2)
__global__ void sae_encode_gemm(const float* __restrict__ X,
                                const float* __restrict__ Enc,
                                const unsigned short* __restrict__ Encbf,
                                const float* __restrict__ bpre,
                                const float* __restrict__ benc,
                                float* __restrict__ zbase)
{
    __shared__ unsigned short lA[128 * 32];
    __shared__ unsigned short lB[128 * 32];
    const int tid  = threadIdx.x;
    const int lane = tid & 63;
    const int wave = tid >> 6;
    const int wx = wave & 1, wy = wave >> 1;
    const int mBase = blockIdx.x * 128;
    const int nBase = blockIdx.y * 128;

    floatx4 acc[4][4];
#pragma unroll
    for (int i = 0; i < 4; ++i)
#pragma unroll
        for (int j = 0; j < 4; ++j) acc[i][j] = (floatx4){0.f, 0.f, 0.f, 0.f};

    const int sRow = tid >> 1;
    const int sCol = (tid & 1) * 16;
    const size_t aRow = (size_t)(nBase + sRow) * H_DIM;
    const size_t bRow = (size_t)(mBase + sRow) * H_DIM;
    unsigned short* sA = &lA[sRow * 32 + sCol];
    unsigned short* sB = &lB[sRow * 32 + sCol];

    const int gR0 = wave * 32 + (lane >> 2);
    const int gR1 = gR0 + 16;
    const int gC  = (lane & 3) * 8;
    const int lOff0 = wave * 1024 + lane * 8;
    const int lOff1 = lOff0 + 512;

    const int quad = lane >> 4;
    const int l15  = lane & 15;

    for (int kt = 0; kt < H_DIM / 32; ++kt) {
        const int k0 = kt * 32;
        ushort8 wa0, wa1, wb0, wb1;
#pragma unroll
        for (int c = 0; c < 2; ++c) {
            float4 a0 = *(const float4*)(X + aRow + k0 + sCol + c * 8);
            float4 a1 = *(const float4*)(X + aRow + k0 + sCol + c * 8 + 4);
            float4 p0 = *(const float4*)(bpre + k0 + sCol + c * 8);
            float4 p1 = *(const float4*)(bpre + k0 + sCol + c * 8 + 4);
            ushort8 wa;
            wa[0] = f2bf(a0.x - p0.x); wa[1] = f2bf(a0.y - p0.y);
            wa[2] = f2bf(a0.z - p0.z); wa[3] = f2bf(a0.w - p0.w);
            wa[4] = f2bf(a1.x - p1.x); wa[5] = f2bf(a1.y - p1.y);
            wa[6] = f2bf(a1.z - p1.z); wa[7] = f2bf(a1.w - p1.w);
            if (c == 0) wa0 = wa; else wa1 = wa;
        }
        if constexpr (!BBF) {
#pragma unroll
            for (int c = 0; c < 2; ++c) {
                float4 b0 = *(const float4*)(Enc + bRow + k0 + sCol + c * 8);
                float4 b1 = *(const float4*)(Enc + bRow + k0 + sCol + c * 8 + 4);
                ushort8 wb;
                wb[0] = f2bf(b0.x); wb[1] = f2bf(b0.y); wb[2] = f2bf(b0.z); wb[3] = f2bf(b0.w);
                wb[4] = f2bf(b1.x); wb[5] = f2bf(b1.y); wb[6] = f2bf(b1.z); wb[7] = f2bf(b1.w);
                if (c == 0) wb0 = wb; else wb1 = wb;
            }
        }
        __syncthreads();
        *(ushort8*)(sA)     = wa0;
        *(ushort8*)(sA + 8) = wa1;
        if constexpr (!BBF) {
            *(ushort8*)(sB)     = wb0;
            *(ushort8*)(sB + 8) = wb1;
        } else {
            gload16(Encbf + (size_t)(mBase + gR0) * H_DIM + k0 + gC, &lB[lOff0]);
            gload16(Encbf + (size_t)(mBase + gR1) * H_DIM + k0 + gC, &lB[lOff1]);
        }
        __syncthreads();
        bf16x8 af[4], bfr[4];
#pragma unroll
        for (int i = 0; i < 4; ++i)
            af[i] = *(const bf16x8*)&lA[(wy * 64 + i * 16 + l15) * 32 + quad * 8];
#pragma unroll
        for (int j = 0; j < 4; ++j)
            bfr[j] = *(const bf16x8*)&lB[(wx * 64 + j * 16 + l15) * 32 + quad * 8];
#pragma unroll
        for (int i = 0; i < 4; ++i)
#pragma unroll
            for (int j = 0; j < 4; ++j)
                acc[i][j] = __builtin_amdgcn_mfma_f32_16x16x32_bf16(af[i], bfr[j], acc[i][j], 0, 0, 0);
    }

#pragma unroll
    for (int i = 0; i < 4; ++i) {
        int nLoc = nBase + wy * 64 + i * 16 + quad * 4;
#pragma unroll
        for (int j = 0; j < 4; ++j) {
            int m = mBase + wx * 64 + j * 16 + l15;
            float bc = benc[m];
#pragma unroll
            for (int r = 0; r < 4; ++r) {
                float v = acc[i][j][r] + bc;
                v = v > 0.f ? v : 0.f;
                zbase[(size_t)(nLoc + r) * M_DIM + m] = v;
            }
        }
    }
}

// full-block decode helper for rare paths (2 h per thread, padded list)
static __device__ __forceinline__ void sae_row_decode(
    const unsigned short* __restrict__ decTb,
    const int* kIdx, const float* kVal,
    int row, int tid, float p0, float p1,
    float* __restrict__ xOut)
{
    float a0 = 0.f, a1 = 0.f;
#pragma unroll 8
    for (int j = 0; j < TOPK; ++j) {
        float v = kVal[j];
        int m = kIdx[j];
        unsigned int d = *(const unsigned int*)(decTb + (size_t)m * H_DIM + tid * 2);
        a0 = fmaf(v, __uint_as_float(d << 16), a0);
        a1 = fmaf(v, __uint_as_float(d & 0xFFFF0000u), a1);
    }
    float2 o; o.x = a0 + p0; o.y = a1 + p1;
    *(float2*)(xOut + (size_t)row * H_DIM + tid * 2) = o;
}

// ---- K2: exact top-64 mask in-place + fused decode.
// Main-path schedule: zero-rewrite stores issued early (drain under compute);
// waves 0-1 run the np-exact band FMA chains while waves 2-3 decode the
// definite keeps; band keeps appended after ranking, short decode tail.
__launch_bounds__(256, 2)
__global__ void sae_topk(float* __restrict__ zbase,
                         const float* __restrict__ X,
                         const float* __restrict__ Enc,
                         const float* __restrict__ bpre,
                         const float* __restrict__ benc,
                         const unsigned short* __restrict__ decTb,
                         float* __restrict__ xOut,
                         int doDec)
{
    __shared__ unsigned int hist[NBINS];      // 8 KB
    __shared__ unsigned int wsum[4];
    __shared__ unsigned int scanb[256];
    __shared__ float xs[H_DIM];
    __shared__ int   bandIdx[BAND_CAP];
    __shared__ float bandVal[BAND_CAP];
    __shared__ int   kIdx[TOPK];
    __shared__ float kVal[TOPK];
    __shared__ int   sBand, sKeep, sBin, sAbove;

    const int tid  = threadIdx.x;
    const int lane = tid & 63;
    const int wave = tid >> 6;
    const int row  = blockIdx.x;

    // coalesced row load: instruction c reads 1KB contiguous across the wave
    float val[16];
    {
        const float4* src = (const float4*)(zbase + (size_t)row * M_DIM);
#pragma unroll
        for (int c = 0; c < 4; ++c) {
            float4 t = src[c * 256 + tid];
            val[c*4+0] = t.x; val[c*4+1] = t.y; val[c*4+2] = t.z; val[c*4+3] = t.w;
        }
    }
    unsigned int u[16];
#pragma unroll
    for (int i = 0; i < 16; ++i) u[i] = __float_as_uint(val[i]);

    // early-issue the X row (hides HBM latency under the histogram)
    float x0 = X[(size_t)row * H_DIM + tid * 2];
    float x1 = X[(size_t)row * H_DIM + tid * 2 + 1];
    float p0 = bpre[tid * 2], p1 = bpre[tid * 2 + 1];

    if (tid == 0) { sBand = 0; sKeep = 0; sBin = -1; }
#pragma unroll
    for (int i = 0; i < NBINS / 256; ++i) hist[tid + i * 256] = 0u;
    __syncthreads();
#pragma unroll
    for (int i = 0; i < 16; ++i)
        if (u[i]) atomicAdd(&hist[u[i] >> 20], 1u);
    __syncthreads();

    // level-1 suffix scan: find bin of 64th-largest, count strictly above
    unsigned int h8[8];
    {
        const int base = tid * 8;
        unsigned int s = 0;
#pragma unroll
        for (int i = 0; i < 8; ++i) { h8[i] = hist[base + i]; s += h8[i]; }
        unsigned int suf = s;
#pragma unroll
        for (int off = 1; off < 64; off <<= 1) {
            unsigned int o = __shfl_down(suf, off);
            if (lane + off < 64) suf += o;
        }
        if (lane == 0) wsum[wave] = suf;
        __syncthreads();
        unsigned int hiW = 0;
        for (int w = wave + 1; w < 4; ++w) hiW += wsum[w];
        suf += hiW;
        if (suf >= (unsigned)TOPK && suf - s < (unsigned)TOPK) {
            unsigned int above = suf - s;
#pragma unroll
            for (int i = 7; i >= 0; --i) {
                if (above + h8[i] >= (unsigned)TOPK) { sBin = base + i; sAbove = (int)above; break; }
                above += h8[i];
            }
        }
        __syncthreads();
    }
    const unsigned int total = wsum[0] + wsum[1] + wsum[2] + wsum[3];

    if (total < (unsigned)TOPK) {
        float4* dst = (float4*)(zbase + (size_t)row * M_DIM);
#pragma unroll
        for (int c = 0; c < 4; ++c) {
            float4 t;
            t.x = val[c*4+0]; t.y = val[c*4+1]; t.z = val[c*4+2]; t.w = val[c*4+3];
            dst[c * 256 + tid] = t;
        }
        if (doDec) {
#pragma unroll
            for (int c = 0; c < 4; ++c)
#pragma unroll
                for (int j = 0; j < 4; ++j)
                    if (val[c*4+j] > 0.f) {
                        int p = atomicAdd(&sKeep, 1);
                        if (p < TOPK) { kIdx[p] = c * 1024 + tid * 4 + j; kVal[p] = val[c*4+j]; }
                    }
            __syncthreads();
            int kc = sKeep; if (kc > TOPK) kc = TOPK;
            if (tid < TOPK && tid >= kc) { kIdx[tid] = 0; kVal[tid] = 0.f; }
            __syncthreads();
            sae_row_decode(decTb, kIdx, kVal, row, tid, p0, p1, xOut);
        }
        return;
    }

    const int b1 = sBin;
    const unsigned int above1 = (unsigned int)sAbove;
    __syncthreads();

    // level-2: refine bits 19..9 within bin b1
#pragma unroll
    for (int i = 0; i < NBINS / 256; ++i) hist[tid + i * 256] = 0u;
    if (tid == 0) sBin = -1;
    __syncthreads();
#pragma unroll
    for (int i = 0; i < 16; ++i)
        if (u[i] && (int)(u[i] >> 20) == b1) atomicAdd(&hist[(u[i] >> 9) & 0x7FFu], 1u);
    __syncthreads();
    const unsigned int Kneed = (unsigned)TOPK - above1;
    {
        const int base = tid * 8;
        unsigned int s = 0;
#pragma unroll
        for (int i = 0; i < 8; ++i) { h8[i] = hist[base + i]; s += h8[i]; }
        unsigned int suf = s;
#pragma unroll
        for (int off = 1; off < 64; off <<= 1) {
            unsigned int o = __shfl_down(suf, off);
            if (lane + off < 64) suf += o;
        }
        if (lane == 0) wsum[wave] = suf;
        __syncthreads();
        unsigned int hiW = 0;
        for (int w = wave + 1; w < 4; ++w) hiW += wsum[w];
        suf += hiW;
        if (suf >= Kneed && suf - s < Kneed) {
            unsigned int above = suf - s;
#pragma unroll
            for (int i = 7; i >= 0; --i) {
                if (above + h8[i] >= Kneed) { sBin = base + i; break; }
                above += h8[i];
            }
        }
        __syncthreads();
    }
    const unsigned int T = ((unsigned int)b1 << 20) | ((unsigned int)sBin << 9);
    const float Tf  = __uint_as_float(T);
    const float Tub = __uint_as_float(T + (1u << 9));

    const float marg = 0.04f + 0.01f * Tub;
    float lo = Tf - marg; if (lo <= 0.f) lo = 1e-12f;
    const float hi = Tub + marg;

    // D count + band collect + xs stage, one barrier
    {
        int d = 0;
#pragma unroll
        for (int i = 0; i < 16; ++i) d += (val[i] > hi) ? 1 : 0;
        for (int off = 32; off >= 1; off >>= 1) d += __shfl_down(d, off);
        if (lane == 0) wsum[wave] = (unsigned int)d;
    }
#pragma unroll
    for (int c = 0; c < 4; ++c)
#pragma unroll
        for (int j = 0; j < 4; ++j) {
            float v = val[c*4+j];
            if (v >= lo && v <= hi) {
                int p = atomicAdd(&sBand, 1);
                if (p < BAND_CAP) bandIdx[p] = c * 1024 + tid * 4 + j;
            }
        }
    xs[tid * 2]     = x0 - p0;
    xs[tid * 2 + 1] = x1 - p1;
    __syncthreads();
    const int D  = (int)(wsum[0] + wsum[1] + wsum[2] + wsum[3]);
    const int Bn = sBand;

    if (Bn > BAND_CAP) {
        // pathological fallback: re-read thread-major (preserves original tie
        // ordering), exact bit-serial radix + quota selection.
        float vold[16]; unsigned int uold[16];
        {
            const float4* src = (const float4*)(zbase + (size_t)row * M_DIM) + tid * 4;
#pragma unroll
            for (int i = 0; i < 4; ++i) {
                float4 t = src[i];
                vold[i*4+0] = t.x; vold[i*4+1] = t.y; vold[i*4+2] = t.z; vold[i*4+3] = t.w;
            }
        }
#pragma unroll
        for (int i = 0; i < 16; ++i) uold[i] = __float_as_uint(vold[i]);

        unsigned int Tx = 0;
        for (int bit = 30; bit >= 0; --bit) {
            unsigned int cand = Tx | (1u << bit);
            int c = 0;
#pragma unroll
            for (int i = 0; i < 16; ++i) c += (uold[i] >= cand) ? 1 : 0;
            for (int off = 32; off >= 1; off >>= 1) c += __shfl_down(c, off);
            __syncthreads();
            if (lane == 0) wsum[wave] = (unsigned int)c;
            __syncthreads();
            if (wsum[0] + wsum[1] + wsum[2] + wsum[3] >= TOPK) Tx = cand;
        }
        int c = 0;
#pragma unroll
        for (int i = 0; i < 16; ++i) c += (uold[i] > Tx) ? 1 : 0;
        for (int off = 32; off >= 1; off >>= 1) c += __shfl_down(c, off);
        __syncthreads();
        if (lane == 0) wsum[wave] = (unsigned int)c;
        __syncthreads();
        unsigned int q = TOPK - (wsum[0] + wsum[1] + wsum[2] + wsum[3]);
        unsigned int myT = 0;
#pragma unroll
        for (int i = 0; i < 16; ++i) myT += (uold[i] == Tx) ? 1u : 0u;
        scanb[tid] = myT;
        __syncthreads();
        if (tid == 0) {
            unsigned int run = 0;
            for (int t = 0; t < 256; ++t) { unsigned int c2 = scanb[t]; scanb[t] = run; run += c2; }
        }
        __syncthreads();
        unsigned int tieRank = scanb[tid];
#pragma unroll
        for (int i = 0; i < 16; ++i) {
            bool isTie = (uold[i] == Tx);
            bool keep  = (uold[i] > Tx) || (isTie && tieRank < q);
            if (isTie) tieRank++;
            zbase[(size_t)row * M_DIM + tid * 16 + i] = keep ? vold[i] : 0.f;
            if (doDec && keep) {
                int p = atomicAdd(&sKeep, 1);
                if (p < TOPK) { kIdx[p] = tid * 16 + i; kVal[p] = vold[i]; }
            }
        }
        if (doDec) {
            __syncthreads();
            int kc = sKeep; if (kc > TOPK) kc = TOPK;
            if (tid < TOPK && tid >= kc) { kIdx[tid] = 0; kVal[tid] = 0.f; }
            __syncthreads();
            sae_row_decode(decTb, kIdx, kVal, row, tid, p0, p1, xOut);
        }
        return;
    }

    // ---- main path, overlapped schedule ----
    // (1) bulk zero-rewrite stores issued now: drain under the chain/decode.
    {
        float4* dst = (float4*)(zbase + (size_t)row * M_DIM);
#pragma unroll
        for (int c = 0; c < 4; ++c) {
            float4 t;
            t.x = val[c*4+0] > hi ? val[c*4+0] : 0.f;
            t.y = val[c*4+1] > hi ? val[c*4+1] : 0.f;
            t.z = val[c*4+2] > hi ? val[c*4+2] : 0.f;
            t.w = val[c*4+3] > hi ? val[c*4+3] : 0.f;
            dst[c * 256 + tid] = t;
        }
    }
    // (2) definite keeps collected now (known pre-chain)
#pragma unroll
    for (int c = 0; c < 4; ++c)
#pragma unroll
        for (int j = 0; j < 4; ++j)
            if (val[c*4+j] > hi) {
                int p = atomicAdd(&sKeep, 1);
                if (p < TOPK) { kIdx[p] = c * 1024 + tid * 4 + j; kVal[p] = val[c*4+j]; }
            }
    __syncthreads();   // kcDef final; zero-writes drained (vmcnt before barrier)
    const int kcDef = (sKeep < TOPK) ? sKeep : TOPK;

    // (3) waves 0-1: np-exact band chains.  waves 2-3: decode definite keeps.
    const int h4 = (tid - 128) * 4;
    float da0 = 0.f, da1 = 0.f, da2 = 0.f, da3 = 0.f;
    if (tid < 128) {
        if (tid < Bn) {
            int m = bandIdx[tid];
            const float* er = Enc + (size_t)m * H_DIM;
            float s = 0.f;
#pragma unroll 8
            for (int k = 0; k < H_DIM; ++k) s = fmaf(xs[k], er[k], s);
            float lg = s + benc[m];
            bandVal[tid] = lg > 0.f ? lg : 0.f;
        }
    } else if (doDec) {
#pragma unroll 4
        for (int j = 0; j < kcDef; ++j) {
            float v = kVal[j];
            int m = kIdx[j];
            uint2 d = *(const uint2*)(decTb + (size_t)m * H_DIM + h4);
            da0 = fmaf(v, __uint_as_float(d.x << 16), da0);
            da1 = fmaf(v, __uint_as_float(d.x & 0xFFFF0000u), da1);
            da2 = fmaf(v, __uint_as_float(d.y << 16), da2);
            da3 = fmaf(v, __uint_as_float(d.y & 0xFFFF0000u), da3);
        }
    }
    __syncthreads();   // bandVal ready

    // (4) rank band candidates; scatter band keeps (z + list)
    if (tid < Bn) {
        float myV = bandVal[tid]; int myM = bandIdx[tid];
        const float eps = 7.2e-8f * myV;
        int r = 0;
        for (int k = 0; k < Bn; ++k) {
            float v = bandVal[k];
            float d = v - myV;
            bool tie = (d <= eps) && (d >= -eps);
            r += ((!tie && v > myV) || (tie && bandIdx[k] < myM)) ? 1 : 0;
        }
        if (r < (TOPK - D)) {
            zbase[(size_t)row * M_DIM + myM] = myV;
            if (doDec) {
                int p = atomicAdd(&sKeep, 1);
                if (p < TOPK) { kIdx[p] = myM; kVal[p] = myV; }
            }
        }
    }
    __syncthreads();   // kc final; band scatter ordered after zero-writes (2 barriers)

    // (5) waves 2-3: decode band-keep tail + write x row
    if (doDec && tid >= 128) {
        int kc = sKeep; if (kc > TOPK) kc = TOPK;
        for (int j = kcDef; j < kc; ++j) {
            float v = kVal[j];
            int m = kIdx[j];
            uint2 d = *(const uint2*)(decTb + (size_t)m * H_DIM + h4);
            da0 = fmaf(v, __uint_as_float(d.x << 16), da0);
            da1 = fmaf(v, __uint_as_float(d.x & 0xFFFF0000u), da1);
            da2 = fmaf(v, __uint_as_float(d.y << 16), da2);
            da3 = fmaf(v, __uint_as_float(d.y & 0xFFFF0000u), da3);
        }
        float4 pp = *(const float4*)(bpre + h4);
        float4 o;
        o.x = da0 + pp.x; o.y = da1 + pp.y; o.z = da2 + pp.z; o.w = da3 + pp.w;
        *(float4*)(xOut + (size_t)row * H_DIM + h4) = o;
    }
}

// ---- K3 fallback (only if ws too small for decTb): rescan masked z row
__launch_bounds__(256, 2)
__global__ void sae_decode_fb(const float* __restrict__ zbase,
                              const float* __restrict__ dec,    // [H, M]
                              const float* __restrict__ bpre,
                              float* __restrict__ xOut)
{
    __shared__ float sVal[4][DEC_CAP];
    __shared__ int   sIdx[4][DEC_CAP];
    __shared__ int   sCnt[4];
    const int lane = threadIdx.x & 63;
    const int wave = threadIdx.x >> 6;
    const int row  = blockIdx.x * 4 + wave;
    if (lane == 0) sCnt[wave] = 0;
    __syncthreads();

    const float* zr = zbase + (size_t)row * M_DIM;
    for (int c = 0; c < 8; ++c) {
        const float4* p4 = (const float4*)(zr + c * 512 + lane * 8);
        float4 t0 = p4[0], t1 = p4[1];
        float tv[8] = {t0.x, t0.y, t0.z, t0.w, t1.x, t1.y, t1.z, t1.w};
#pragma unroll
        for (int e = 0; e < 8; ++e) {
            if (tv[e] != 0.f) {
                int p = atomicAdd(&sCnt[wave], 1);
                if (p < DEC_CAP) { sIdx[wave][p] = c * 512 + lane * 8 + e; sVal[wave][p] = tv[e]; }
            }
        }
    }
    __syncthreads();
    int cnt = sCnt[wave]; if (cnt > DEC_CAP) cnt = DEC_CAP;

    const int hBase = lane * 8;
    float acc[8] = {0.f, 0.f, 0.f, 0.f, 0.f, 0.f, 0.f, 0.f};
    for (int j = 0; j < cnt; ++j) {
        float v = sVal[wave][j];
        int m   = sIdx[wave][j];
#pragma unroll
        for (int e = 0; e < 8; ++e)
            acc[e] += v * dec[(size_t)(hBase + e) * M_DIM + m];
    }
    float4 o0, o1;
    const float* pf = bpre + hBase;
    o0.x = acc[0] + pf[0]; o0.y = acc[1] + pf[1]; o0.z = acc[2] + pf[2]; o0.w = acc[3] + pf[3];
    o1.x = acc[4] + pf[4]; o1.y = acc[5] + pf[5]; o1.z = acc[6] + pf[6]; o1.w = acc[7] + pf[7];
    float* xr = xOut + (size_t)row * H_DIM + hBase;
    ((float4*)xr)[0] = o0; ((float4*)xr)[1] = o1;
}

extern "C" void kernel_launch(void* const* d_in, const int* in_sizes, int n_in,
                              void* d_out, int out_size, void* d_ws, size_t ws_size,
                              hipStream_t stream)
{
    const float* zL   = (const float*)d_in[0]; // [N, H]
    const float* enc  = (const float*)d_in[1]; // [M, H]
    const float* dec  = (const float*)d_in[2]; // [H, M]
    const float* bpre = (const float*)d_in[3]; // [H]
    const float* benc = (const float*)d_in[4]; // [M]
    const int N = in_sizes[0] / H_DIM;         // 16384

    float* zOut = (float*)d_out;               // [N, M]
    float* xOut = zOut + (size_t)N * M_DIM;    // [N, H]

    const size_t dectB  = (size_t)M_DIM * H_DIM * 2;   // 4 MB bf16 decT
    const size_t encbB  = (size_t)M_DIM * H_DIM * 2;   // 4 MB bf16 Enc
    const size_t xbfB   = (size_t)N * H_DIM * 2;       // 16 MB bf16 (X - bpre)

    unsigned short *decTb = nullptr, *Encb = nullptr, *Xb = nullptr;
    size_t off = 0;
    if (ws_size >= off + dectB) { decTb = (unsigned short*)((char*)d_ws + off); off += dectB; }
    if (decTb && ws_size >= off + encbB) { Encb = (unsigned short*)((char*)d_ws + off); off += encbB; }
    if (Encb && ws_size >= off + xbfB)   { Xb   = (unsigned short*)((char*)d_ws + off); off += xbfB; }

    if (decTb) sae_conv_decT<<<dim3(M_DIM / 64, H_DIM / 64), 256, 0, stream>>>(dec, decTb);
    if (Encb)  sae_conv_enc<<<(M_DIM * H_DIM) / 2048, 256, 0, stream>>>(enc, Encb);
    if (Xb)    sae_conv_x<<<(int)(((size_t)N * H_DIM) / 2048), 256, 0, stream>>>(zL, bpre, Xb);

    dim3 eg(M_DIM / 128, N / 128);
    if (Xb)        sae_encode_gemm64<<<eg, 256, 0, stream>>>(Xb, Encb, benc, zOut);
    else if (Encb) sae_encode_gemm<1><<<eg, 256, 0, stream>>>(zL, enc, Encb, bpre, benc, zOut);
    else           sae_encode_gemm<0><<<eg, 256, 0, stream>>>(zL, enc, nullptr, bpre, benc, zOut);

    sae_topk<<<N, 256, 0, stream>>>(zOut, zL, enc, bpre, benc, decTb, xOut, decTb ? 1 : 0);
    if (!decTb) sae_decode_fb<<<N / 4, 256, 0, stream>>>(zOut, dec, bpre, xOut);
}

// Round 4
// 802.294 us; speedup vs baseline: 1.1074x; 1.1074x over previous
//
#include <hip/hip_runtime.h>
#include <stdint.h>
#include <stddef.h>

#define H_DIM 512
#define M_DIM 4096
#define TOPK  64
#define BAND_CAP 128
#define DEC_CAP 96
#define NBINS 2048

typedef __attribute__((ext_vector_type(8))) short bf16x8;
typedef __attribute__((ext_vector_type(4))) float floatx4;
typedef __attribute__((ext_vector_type(8))) unsigned short ushort8;

static __device__ __forceinline__ unsigned short f2bf(float f) {
    union { float ff; unsigned int i; } v; v.ff = f;
    unsigned int u = v.i;
    u += 0x7FFFu + ((u >> 16) & 1u);   // RNE
    return (unsigned short)(u >> 16);
}

static __device__ __forceinline__ void gload16(const void* g, void* l) {
    __builtin_amdgcn_global_load_lds(
        (const __attribute__((address_space(1))) unsigned int*)g,
        (__attribute__((address_space(3))) unsigned int*)l, 16, 0, 0);
}

// ---- prep: Xbf[n*H+h] = bf16(X - bpre)  (bit-identical f2bf to inline path)
__global__ void sae_conv_x(const float* __restrict__ X, const float* __restrict__ bpre,
                           unsigned short* __restrict__ Xbf) {
    int g = (blockIdx.x * 256 + threadIdx.x) * 8;
    int h = g & (H_DIM - 1);
    float4 a0 = *(const float4*)(X + g);
    float4 a1 = *(const float4*)(X + g + 4);
    float4 p0 = *(const float4*)(bpre + h);
    float4 p1 = *(const float4*)(bpre + h + 4);
    ushort8 o;
    o[0] = f2bf(a0.x - p0.x); o[1] = f2bf(a0.y - p0.y);
    o[2] = f2bf(a0.z - p0.z); o[3] = f2bf(a0.w - p0.w);
    o[4] = f2bf(a1.x - p1.x); o[5] = f2bf(a1.y - p1.y);
    o[6] = f2bf(a1.z - p1.z); o[7] = f2bf(a1.w - p1.w);
    *(ushort8*)(Xbf + g) = o;
}

// ---- prep: Encbf = bf16(Enc) elementwise
__global__ void sae_conv_enc(const float* __restrict__ Enc, unsigned short* __restrict__ Eb) {
    int g = (blockIdx.x * 256 + threadIdx.x) * 8;
    float4 b0 = *(const float4*)(Enc + g);
    float4 b1 = *(const float4*)(Enc + g + 4);
    ushort8 o;
    o[0] = f2bf(b0.x); o[1] = f2bf(b0.y); o[2] = f2bf(b0.z); o[3] = f2bf(b0.w);
    o[4] = f2bf(b1.x); o[5] = f2bf(b1.y); o[6] = f2bf(b1.z); o[7] = f2bf(b1.w);
    *(ushort8*)(Eb + g) = o;
}

// ---- prep: decTb[m*H + h] = bf16(dec[h*M + m])  via LDS tile transpose
__global__ void sae_conv_decT(const float* __restrict__ dec, unsigned short* __restrict__ decTb) {
    __shared__ float tile[64][65];
    const int m0 = blockIdx.x * 64;
    const int h0 = blockIdx.y * 64;
    const int tid = threadIdx.x;
#pragma unroll
    for (int it = 0; it < 16; ++it) {
        int r = it * 4 + (tid >> 6);      // h-local
        int c = tid & 63;                  // m-local (coalesced)
        tile[r][c] = dec[(size_t)(h0 + r) * M_DIM + m0 + c];
    }
    __syncthreads();
    const int ml = tid >> 2;
    const int q  = tid & 3;
    ushort8 o0, o1;
#pragma unroll
    for (int e = 0; e < 8; ++e) o0[e] = f2bf(tile[q * 16 + e][ml]);
#pragma unroll
    for (int e = 0; e < 8; ++e) o1[e] = f2bf(tile[q * 16 + 8 + e][ml]);
    unsigned short* out = decTb + (size_t)(m0 + ml) * H_DIM + h0 + q * 16;
    *(ushort8*)(out)     = o0;
    *(ushort8*)(out + 8) = o1;
}

// ---- K1 fast path: BK=64 GEMM from precomputed bf16 arrays, XCD-swizzled grid.
// Bijective swizzle (nwg=4096, 4096%8==0): XCD k owns swz ids [k*512,(k+1)*512)
// = 16 consecutive n-tiles, sweeping all 32 m-tiles inner. Per-XCD L2 working
// set ~= Encbf(4MB, resident) + 1-2 A-tiles -> LLC re-read traffic ~1GB -> ~50MB.
// K-chunk order (0,32,64,...) identical to BK=32 path -> z bit-identical.
__launch_bounds__(256, 2)
__global__ void sae_encode_gemm64(const unsigned short* __restrict__ Xbf,   // [N,H] bf16
                                  const unsigned short* __restrict__ Encbf, // [M,H] bf16
                                  const float* __restrict__ benc,
                                  float* __restrict__ zbase)
{
    __shared__ unsigned short lA[128 * 64];   // 16 KB
    __shared__ unsigned short lB[128 * 64];   // 16 KB
    const int tid  = threadIdx.x;
    const int lane = tid & 63;
    const int wave = tid >> 6;
    const int wx = wave & 1, wy = wave >> 1;

    // XCD-aware bijective block swizzle (T1): contiguous chunk per XCD
    const int bid = blockIdx.x;                 // 0..4095
    const int swz = (bid & 7) * 512 + (bid >> 3);
    const int mBase = (swz & 31) * 128;         // m-tile inner (B panel hot in L2)
    const int nBase = (swz >> 5) * 128;         // n-tile outer

    floatx4 acc[4][4];
#pragma unroll
    for (int i = 0; i < 4; ++i)
#pragma unroll
        for (int j = 0; j < 4; ++j) acc[i][j] = (floatx4){0.f, 0.f, 0.f, 0.f};

    // staging map: instr j stages rows wave*32 + j*8 + (lane>>3), cols (lane&7)*8
    // LDS elem offset = wave*2048 + j*512 + lane*8 (linear row*64+col)
    const int gRow = wave * 32 + (lane >> 3);
    const int gCol = (lane & 7) * 8;
    const int lOff = wave * 2048 + lane * 8;
    const unsigned short* gA = Xbf  + (size_t)(nBase + gRow) * H_DIM + gCol;
    const unsigned short* gB = Encbf + (size_t)(mBase + gRow) * H_DIM + gCol;

    const int quad = lane >> 4;
    const int l15  = lane & 15;

    for (int kt = 0; kt < H_DIM / 64; ++kt) {
        const int k0 = kt * 64;
        __syncthreads();
#pragma unroll
        for (int j = 0; j < 4; ++j)
            gload16(gA + (size_t)(j * 8) * H_DIM + k0, &lA[lOff + j * 512]);
#pragma unroll
        for (int j = 0; j < 4; ++j)
            gload16(gB + (size_t)(j * 8) * H_DIM + k0, &lB[lOff + j * 512]);
        __syncthreads();
#pragma unroll
        for (int kk = 0; kk < 2; ++kk) {
            bf16x8 af[4], bfr[4];
#pragma unroll
            for (int i = 0; i < 4; ++i)
                af[i] = *(const bf16x8*)&lA[(wy * 64 + i * 16 + l15) * 64 + kk * 32 + quad * 8];
#pragma unroll
            for (int j = 0; j < 4; ++j)
                bfr[j] = *(const bf16x8*)&lB[(wx * 64 + j * 16 + l15) * 64 + kk * 32 + quad * 8];
#pragma unroll
            for (int i = 0; i < 4; ++i)
#pragma unroll
                for (int j = 0; j < 4; ++j)
                    acc[i][j] = __builtin_amdgcn_mfma_f32_16x16x32_bf16(af[i], bfr[j], acc[i][j], 0, 0, 0);
        }
    }

#pragma unroll
    for (int i = 0; i < 4; ++i) {
        int nLoc = nBase + wy * 64 + i * 16 + quad * 4;
#pragma unroll
        for (int j = 0; j < 4; ++j) {
            int m = mBase + wx * 64 + j * 16 + l15;
            float bc = benc[m];
#pragma unroll
            for (int r = 0; r < 4; ++r) {
                float v = acc[i][j][r] + bc;
                v = v > 0.f ? v : 0.f;
                zbase[(size_t)(nLoc + r) * M_DIM + m] = v;
            }
        }
    }
}

// ---- K1 fallback (small ws): BK=32 kernel with inline f2bf
template<int BBF>
__launch_bounds__(256, 2)
__global__ void sae_encode_gemm(const float* __restrict__ X,
                                const float* __restrict__ Enc,
                                const unsigned short* __restrict__ Encbf,
                                const float* __restrict__ bpre,
                                const float* __restrict__ benc,
                                float* __restrict__ zbase)
{
    __shared__ unsigned short lA[128 * 32];
    __shared__ unsigned short lB[128 * 32];
    const int tid  = threadIdx.x;
    const int lane = tid & 63;
    const int wave = tid >> 6;
    const int wx = wave & 1, wy = wave >> 1;
    const int mBase = blockIdx.x * 128;
    const int nBase = blockIdx.y * 128;

    floatx4 acc[4][4];
#pragma unroll
    for (int i = 0; i < 4; ++i)
#pragma unroll
        for (int j = 0; j < 4; ++j) acc[i][j] = (floatx4){0.f, 0.f, 0.f, 0.f};

    const int sRow = tid >> 1;
    const int sCol = (tid & 1) * 16;
    const size_t aRow = (size_t)(nBase + sRow) * H_DIM;
    const size_t bRow = (size_t)(mBase + sRow) * H_DIM;
    unsigned short* sA = &lA[sRow * 32 + sCol];
    unsigned short* sB = &lB[sRow * 32 + sCol];

    const int gR0 = wave * 32 + (lane >> 2);
    const int gR1 = gR0 + 16;
    const int gC  = (lane & 3) * 8;
    const int lOff0 = wave * 1024 + lane * 8;
    const int lOff1 = lOff0 + 512;

    const int quad = lane >> 4;
    const int l15  = lane & 15;

    for (int kt = 0; kt < H_DIM / 32; ++kt) {
        const int k0 = kt * 32;
        ushort8 wa0, wa1, wb0, wb1;
#pragma unroll
        for (int c = 0; c < 2; ++c) {
            float4 a0 = *(const float4*)(X + aRow + k0 + sCol + c * 8);
            float4 a1 = *(const float4*)(X + aRow + k0 + sCol + c * 8 + 4);
            float4 p0 = *(const float4*)(bpre + k0 + sCol + c * 8);
            float4 p1 = *(const float4*)(bpre + k0 + sCol + c * 8 + 4);
            ushort8 wa;
            wa[0] = f2bf(a0.x - p0.x); wa[1] = f2bf(a0.y - p0.y);
            wa[2] = f2bf(a0.z - p0.z); wa[3] = f2bf(a0.w - p0.w);
            wa[4] = f2bf(a1.x - p1.x); wa[5] = f2bf(a1.y - p1.y);
            wa[6] = f2bf(a1.z - p1.z); wa[7] = f2bf(a1.w - p1.w);
            if (c == 0) wa0 = wa; else wa1 = wa;
        }
        if constexpr (!BBF) {
#pragma unroll
            for (int c = 0; c < 2; ++c) {
                float4 b0 = *(const float4*)(Enc + bRow + k0 + sCol + c * 8);
                float4 b1 = *(const float4*)(Enc + bRow + k0 + sCol + c * 8 + 4);
                ushort8 wb;
                wb[0] = f2bf(b0.x); wb[1] = f2bf(b0.y); wb[2] = f2bf(b0.z); wb[3] = f2bf(b0.w);
                wb[4] = f2bf(b1.x); wb[5] = f2bf(b1.y); wb[6] = f2bf(b1.z); wb[7] = f2bf(b1.w);
                if (c == 0) wb0 = wb; else wb1 = wb;
            }
        }
        __syncthreads();
        *(ushort8*)(sA)     = wa0;
        *(ushort8*)(sA + 8) = wa1;
        if constexpr (!BBF) {
            *(ushort8*)(sB)     = wb0;
            *(ushort8*)(sB + 8) = wb1;
        } else {
            gload16(Encbf + (size_t)(mBase + gR0) * H_DIM + k0 + gC, &lB[lOff0]);
            gload16(Encbf + (size_t)(mBase + gR1) * H_DIM + k0 + gC, &lB[lOff1]);
        }
        __syncthreads();
        bf16x8 af[4], bfr[4];
#pragma unroll
        for (int i = 0; i < 4; ++i)
            af[i] = *(const bf16x8*)&lA[(wy * 64 + i * 16 + l15) * 32 + quad * 8];
#pragma unroll
        for (int j = 0; j < 4; ++j)
            bfr[j] = *(const bf16x8*)&lB[(wx * 64 + j * 16 + l15) * 32 + quad * 8];
#pragma unroll
        for (int i = 0; i < 4; ++i)
#pragma unroll
            for (int j = 0; j < 4; ++j)
                acc[i][j] = __builtin_amdgcn_mfma_f32_16x16x32_bf16(af[i], bfr[j], acc[i][j], 0, 0, 0);
    }

#pragma unroll
    for (int i = 0; i < 4; ++i) {
        int nLoc = nBase + wy * 64 + i * 16 + quad * 4;
#pragma unroll
        for (int j = 0; j < 4; ++j) {
            int m = mBase + wx * 64 + j * 16 + l15;
            float bc = benc[m];
#pragma unroll
            for (int r = 0; r < 4; ++r) {
                float v = acc[i][j][r] + bc;
                v = v > 0.f ? v : 0.f;
                zbase[(size_t)(nLoc + r) * M_DIM + m] = v;
            }
        }
    }
}

// fused decode: x_tgt row from the <=64 keeps in LDS, bf16 decT gathers (L2-resident).
// List must be padded to TOPK with (idx=0, val=0) before calling (val=0 contributes 0).
static __device__ __forceinline__ void sae_row_decode(
    const unsigned short* __restrict__ decTb,
    const int* kIdx, const float* kVal,
    int row, int tid, float p0, float p1,
    float* __restrict__ xOut)
{
    float a0 = 0.f, a1 = 0.f;
#pragma unroll 8
    for (int j = 0; j < TOPK; ++j) {
        float v = kVal[j];
        int m = kIdx[j];
        unsigned int d = *(const unsigned int*)(decTb + (size_t)m * H_DIM + tid * 2);
        a0 = fmaf(v, __uint_as_float(d << 16), a0);
        a1 = fmaf(v, __uint_as_float(d & 0xFFFF0000u), a1);
    }
    float2 o; o.x = a0 + p0; o.y = a1 + p1;
    *(float2*)(xOut + (size_t)row * H_DIM + tid * 2) = o;
}

// ---- K2: exact top-64 mask in-place (+ fused decode when decTb available).
// Round-2-measured structure (426us): histogram threshold, band recompute,
// rank, bulk rewrite, full-block decode at the end.
__launch_bounds__(256, 2)
__global__ void sae_topk(float* __restrict__ zbase,
                         const float* __restrict__ X,
                         const float* __restrict__ Enc,
                         const float* __restrict__ bpre,
                         const float* __restrict__ benc,
                         const unsigned short* __restrict__ decTb,
                         float* __restrict__ xOut,
                         int doDec)
{
    __shared__ unsigned int hist[NBINS];      // 8 KB
    __shared__ unsigned int wsum[4];
    __shared__ unsigned int scanb[256];
    __shared__ float xs[H_DIM];
    __shared__ int   bandIdx[BAND_CAP];
    __shared__ float bandVal[BAND_CAP];
    __shared__ int   kIdx[TOPK];
    __shared__ float kVal[TOPK];
    __shared__ int   sBand, sKeep, sBin, sAbove;

    const int tid  = threadIdx.x;
    const int lane = tid & 63;
    const int wave = tid >> 6;
    const int row  = blockIdx.x;

    // coalesced row load: instruction c reads 1KB contiguous across the wave
    float val[16];
    {
        const float4* src = (const float4*)(zbase + (size_t)row * M_DIM);
#pragma unroll
        for (int c = 0; c < 4; ++c) {
            float4 t = src[c * 256 + tid];
            val[c*4+0] = t.x; val[c*4+1] = t.y; val[c*4+2] = t.z; val[c*4+3] = t.w;
        }
    }
    unsigned int u[16];
#pragma unroll
    for (int i = 0; i < 16; ++i) u[i] = __float_as_uint(val[i]);

    // early-issue the X row (hides HBM latency under the histogram)
    float x0 = X[(size_t)row * H_DIM + tid * 2];
    float x1 = X[(size_t)row * H_DIM + tid * 2 + 1];
    float p0 = bpre[tid * 2], p1 = bpre[tid * 2 + 1];

    if (tid == 0) { sBand = 0; sKeep = 0; sBin = -1; }
#pragma unroll
    for (int i = 0; i < NBINS / 256; ++i) hist[tid + i * 256] = 0u;
    __syncthreads();
#pragma unroll
    for (int i = 0; i < 16; ++i)
        if (u[i]) atomicAdd(&hist[u[i] >> 20], 1u);
    __syncthreads();

    // level-1 suffix scan: find bin of 64th-largest, count strictly above
    unsigned int h8[8];
    {
        const int base = tid * 8;
        unsigned int s = 0;
#pragma unroll
        for (int i = 0; i < 8; ++i) { h8[i] = hist[base + i]; s += h8[i]; }
        unsigned int suf = s;
#pragma unroll
        for (int off = 1; off < 64; off <<= 1) {
            unsigned int o = __shfl_down(suf, off);
            if (lane + off < 64) suf += o;
        }
        if (lane == 0) wsum[wave] = suf;
        __syncthreads();
        unsigned int hiW = 0;
        for (int w = wave + 1; w < 4; ++w) hiW += wsum[w];
        suf += hiW;
        if (suf >= (unsigned)TOPK && suf - s < (unsigned)TOPK) {
            unsigned int above = suf - s;
#pragma unroll
            for (int i = 7; i >= 0; --i) {
                if (above + h8[i] >= (unsigned)TOPK) { sBin = base + i; sAbove = (int)above; break; }
                above += h8[i];
            }
        }
        __syncthreads();
    }
    const unsigned int total = wsum[0] + wsum[1] + wsum[2] + wsum[3];

    if (total < (unsigned)TOPK) {
        float4* dst = (float4*)(zbase + (size_t)row * M_DIM);
#pragma unroll
        for (int c = 0; c < 4; ++c) {
            float4 t;
            t.x = val[c*4+0]; t.y = val[c*4+1]; t.z = val[c*4+2]; t.w = val[c*4+3];
            dst[c * 256 + tid] = t;
        }
        if (doDec) {
#pragma unroll
            for (int c = 0; c < 4; ++c)
#pragma unroll
                for (int j = 0; j < 4; ++j)
                    if (val[c*4+j] > 0.f) {
                        int p = atomicAdd(&sKeep, 1);
                        if (p < TOPK) { kIdx[p] = c * 1024 + tid * 4 + j; kVal[p] = val[c*4+j]; }
                    }
            __syncthreads();
            int kc = sKeep; if (kc > TOPK) kc = TOPK;
            if (tid < TOPK && tid >= kc) { kIdx[tid] = 0; kVal[tid] = 0.f; }
            __syncthreads();
            sae_row_decode(decTb, kIdx, kVal, row, tid, p0, p1, xOut);
        }
        return;
    }

    const int b1 = sBin;
    const unsigned int above1 = (unsigned int)sAbove;
    __syncthreads();

    // level-2: refine bits 19..9 within bin b1
#pragma unroll
    for (int i = 0; i < NBINS / 256; ++i) hist[tid + i * 256] = 0u;
    if (tid == 0) sBin = -1;
    __syncthreads();
#pragma unroll
    for (int i = 0; i < 16; ++i)
        if (u[i] && (int)(u[i] >> 20) == b1) atomicAdd(&hist[(u[i] >> 9) & 0x7FFu], 1u);
    __syncthreads();
    const unsigned int Kneed = (unsigned)TOPK - above1;
    {
        const int base = tid * 8;
        unsigned int s = 0;
#pragma unroll
        for (int i = 0; i < 8; ++i) { h8[i] = hist[base + i]; s += h8[i]; }
        unsigned int suf = s;
#pragma unroll
        for (int off = 1; off < 64; off <<= 1) {
            unsigned int o = __shfl_down(suf, off);
            if (lane + off < 64) suf += o;
        }
        if (lane == 0) wsum[wave] = suf;
        __syncthreads();
        unsigned int hiW = 0;
        for (int w = wave + 1; w < 4; ++w) hiW += wsum[w];
        suf += hiW;
        if (suf >= Kneed && suf - s < Kneed) {
            unsigned int above = suf - s;
#pragma unroll
            for (int i = 7; i >= 0; --i) {
                if (above + h8[i] >= Kneed) { sBin = base + i; break; }
                above += h8[i];
            }
        }
        __syncthreads();
    }
    const unsigned int T = ((unsigned int)b1 << 20) | ((unsigned int)sBin << 9);
    const float Tf  = __uint_as_float(T);
    const float Tub = __uint_as_float(T + (1u << 9));

    const float marg = 0.04f + 0.01f * Tub;
    float lo = Tf - marg; if (lo <= 0.f) lo = 1e-12f;
    const float hi = Tub + marg;

    // D count + band collect + xs stage, one barrier
    {
        int d = 0;
#pragma unroll
        for (int i = 0; i < 16; ++i) d += (val[i] > hi) ? 1 : 0;
        for (int off = 32; off >= 1; off >>= 1) d += __shfl_down(d, off);
        if (lane == 0) wsum[wave] = (unsigned int)d;
    }
#pragma unroll
    for (int c = 0; c < 4; ++c)
#pragma unroll
        for (int j = 0; j < 4; ++j) {
            float v = val[c*4+j];
            if (v >= lo && v <= hi) {
                int p = atomicAdd(&sBand, 1);
                if (p < BAND_CAP) bandIdx[p] = c * 1024 + tid * 4 + j;
            }
        }
    xs[tid * 2]     = x0 - p0;
    xs[tid * 2 + 1] = x1 - p1;
    __syncthreads();
    const int D  = (int)(wsum[0] + wsum[1] + wsum[2] + wsum[3]);
    const int Bn = sBand;

    if (Bn > BAND_CAP) {
        // pathological fallback: re-read thread-major (preserves original tie
        // ordering), exact bit-serial radix + quota selection.
        float vold[16]; unsigned int uold[16];
        {
            const float4* src = (const float4*)(zbase + (size_t)row * M_DIM) + tid * 4;
#pragma unroll
            for (int i = 0; i < 4; ++i) {
                float4 t = src[i];
                vold[i*4+0] = t.x; vold[i*4+1] = t.y; vold[i*4+2] = t.z; vold[i*4+3] = t.w;
            }
        }
#pragma unroll
        for (int i = 0; i < 16; ++i) uold[i] = __float_as_uint(vold[i]);

        unsigned int Tx = 0;
        for (int bit = 30; bit >= 0; --bit) {
            unsigned int cand = Tx | (1u << bit);
            int c = 0;
#pragma unroll
            for (int i = 0; i < 16; ++i) c += (uold[i] >= cand) ? 1 : 0;
            for (int off = 32; off >= 1; off >>= 1) c += __shfl_down(c, off);
            __syncthreads();
            if (lane == 0) wsum[wave] = (unsigned int)c;
            __syncthreads();
            if (wsum[0] + wsum[1] + wsum[2] + wsum[3] >= TOPK) Tx = cand;
        }
        int c = 0;
#pragma unroll
        for (int i = 0; i < 16; ++i) c += (uold[i] > Tx) ? 1 : 0;
        for (int off = 32; off >= 1; off >>= 1) c += __shfl_down(c, off);
        __syncthreads();
        if (lane == 0) wsum[wave] = (unsigned int)c;
        __syncthreads();
        unsigned int q = TOPK - (wsum[0] + wsum[1] + wsum[2] + wsum[3]);
        unsigned int myT = 0;
#pragma unroll
        for (int i = 0; i < 16; ++i) myT += (uold[i] == Tx) ? 1u : 0u;
        scanb[tid] = myT;
        __syncthreads();
        if (tid == 0) {
            unsigned int run = 0;
            for (int t = 0; t < 256; ++t) { unsigned int c2 = scanb[t]; scanb[t] = run; run += c2; }
        }
        __syncthreads();
        unsigned int tieRank = scanb[tid];
#pragma unroll
        for (int i = 0; i < 16; ++i) {
            bool isTie = (uold[i] == Tx);
            bool keep  = (uold[i] > Tx) || (isTie && tieRank < q);
            if (isTie) tieRank++;
            zbase[(size_t)row * M_DIM + tid * 16 + i] = keep ? vold[i] : 0.f;
            if (doDec && keep) {
                int p = atomicAdd(&sKeep, 1);
                if (p < TOPK) { kIdx[p] = tid * 16 + i; kVal[p] = vold[i]; }
            }
        }
        if (doDec) {
            __syncthreads();
            int kc = sKeep; if (kc > TOPK) kc = TOPK;
            if (tid < TOPK && tid >= kc) { kIdx[tid] = 0; kVal[tid] = 0.f; }
            __syncthreads();
            sae_row_decode(decTb, kIdx, kVal, row, tid, p0, p1, xOut);
        }
        return;
    }

    // np-candidate fp32 logit: single sequential FMA chain k=0..511
    if (tid < Bn) {
        int m = bandIdx[tid];
        const float* er = Enc + (size_t)m * H_DIM;
        float s = 0.f;
#pragma unroll 8
        for (int k = 0; k < H_DIM; ++k) s = fmaf(xs[k], er[k], s);
        float lg = s + benc[m];
        bandVal[tid] = lg > 0.f ? lg : 0.f;
    }
    __syncthreads();

    // quota rank within band: value desc; ties within 0.6 ulp -> lower index
    int keepB = 0; float myV = 0.f; int myM = -1;
    if (tid < Bn) {
        myV = bandVal[tid]; myM = bandIdx[tid];
        const float eps = 7.2e-8f * myV;
        int r = 0;
        for (int k = 0; k < Bn; ++k) {
            float v = bandVal[k];
            float d = v - myV;
            bool tie = (d <= eps) && (d >= -eps);
            r += ((!tie && v > myV) || (tie && bandIdx[k] < myM)) ? 1 : 0;
        }
        keepB = (r < (TOPK - D)) ? 1 : 0;
    }

    // bulk rewrite (coalesced): definite keeps retain stored value, else 0
    {
        float4* dst = (float4*)(zbase + (size_t)row * M_DIM);
#pragma unroll
        for (int c = 0; c < 4; ++c) {
            float4 t;
            t.x = val[c*4+0] > hi ? val[c*4+0] : 0.f;
            t.y = val[c*4+1] > hi ? val[c*4+1] : 0.f;
            t.z = val[c*4+2] > hi ? val[c*4+2] : 0.f;
            t.w = val[c*4+3] > hi ? val[c*4+3] : 0.f;
            dst[c * 256 + tid] = t;
        }
        if (doDec) {
#pragma unroll
            for (int c = 0; c < 4; ++c)
#pragma unroll
                for (int j = 0; j < 4; ++j)
                    if (val[c*4+j] > hi) {
                        int p = atomicAdd(&sKeep, 1);
                        if (p < TOPK) { kIdx[p] = c * 1024 + tid * 4 + j; kVal[p] = val[c*4+j]; }
                    }
        }
    }
    __syncthreads();   // order zero-writes before band scatter (WAW)
    if (tid < Bn && keepB) {
        zbase[(size_t)row * M_DIM + myM] = myV;
        if (doDec) {
            int p = atomicAdd(&sKeep, 1);
            if (p < TOPK) { kIdx[p] = myM; kVal[p] = myV; }
        }
    }
    if (doDec) {
        __syncthreads();
        int kc = sKeep; if (kc > TOPK) kc = TOPK;
        if (tid < TOPK && tid >= kc) { kIdx[tid] = 0; kVal[tid] = 0.f; }
        __syncthreads();
        sae_row_decode(decTb, kIdx, kVal, row, tid, p0, p1, xOut);
    }
}

// ---- K3 fallback (only if ws too small for decTb): rescan masked z row
__launch_bounds__(256, 2)
__global__ void sae_decode_fb(const float* __restrict__ zbase,
                              const float* __restrict__ dec,    // [H, M]
                              const float* __restrict__ bpre,
                              float* __restrict__ xOut)
{
    __shared__ float sVal[4][DEC_CAP];
    __shared__ int   sIdx[4][DEC_CAP];
    __shared__ int   sCnt[4];
    const int lane = threadIdx.x & 63;
    const int wave = threadIdx.x >> 6;
    const int row  = blockIdx.x * 4 + wave;
    if (lane == 0) sCnt[wave] = 0;
    __syncthreads();

    const float* zr = zbase + (size_t)row * M_DIM;
    for (int c = 0; c < 8; ++c) {
        const float4* p4 = (const float4*)(zr + c * 512 + lane * 8);
        float4 t0 = p4[0], t1 = p4[1];
        float tv[8] = {t0.x, t0.y, t0.z, t0.w, t1.x, t1.y, t1.z, t1.w};
#pragma unroll
        for (int e = 0; e < 8; ++e) {
            if (tv[e] != 0.f) {
                int p = atomicAdd(&sCnt[wave], 1);
                if (p < DEC_CAP) { sIdx[wave][p] = c * 512 + lane * 8 + e; sVal[wave][p] = tv[e]; }
            }
        }
    }
    __syncthreads();
    int cnt = sCnt[wave]; if (cnt > DEC_CAP) cnt = DEC_CAP;

    const int hBase = lane * 8;
    float acc[8] = {0.f, 0.f, 0.f, 0.f, 0.f, 0.f, 0.f, 0.f};
    for (int j = 0; j < cnt; ++j) {
        float v = sVal[wave][j];
        int m   = sIdx[wave][j];
#pragma unroll
        for (int e = 0; e < 8; ++e)
            acc[e] += v * dec[(size_t)(hBase + e) * M_DIM + m];
    }
    float4 o0, o1;
    const float* pf = bpre + hBase;
    o0.x = acc[0] + pf[0]; o0.y = acc[1] + pf[1]; o0.z = acc[2] + pf[2]; o0.w = acc[3] + pf[3];
    o1.x = acc[4] + pf[4]; o1.y = acc[5] + pf[5]; o1.z = acc[6] + pf[6]; o1.w = acc[7] + pf[7];
    float* xr = xOut + (size_t)row * H_DIM + hBase;
    ((float4*)xr)[0] = o0; ((float4*)xr)[1] = o1;
}

extern "C" void kernel_launch(void* const* d_in, const int* in_sizes, int n_in,
                              void* d_out, int out_size, void* d_ws, size_t ws_size,
                              hipStream_t stream)
{
    const float* zL   = (const float*)d_in[0]; // [N, H]
    const float* enc  = (const float*)d_in[1]; // [M, H]
    const float* dec  = (const float*)d_in[2]; // [H, M]
    const float* bpre = (const float*)d_in[3]; // [H]
    const float* benc = (const float*)d_in[4]; // [M]
    const int N = in_sizes[0] / H_DIM;         // 16384

    float* zOut = (float*)d_out;               // [N, M]
    float* xOut = zOut + (size_t)N * M_DIM;    // [N, H]

    const size_t dectB  = (size_t)M_DIM * H_DIM * 2;   // 4 MB bf16 decT
    const size_t encbB  = (size_t)M_DIM * H_DIM * 2;   // 4 MB bf16 Enc
    const size_t xbfB   = (size_t)N * H_DIM * 2;       // 16 MB bf16 (X - bpre)

    unsigned short *decTb = nullptr, *Encb = nullptr, *Xb = nullptr;
    size_t off = 0;
    if (ws_size >= off + dectB) { decTb = (unsigned short*)((char*)d_ws + off); off += dectB; }
    if (decTb && ws_size >= off + encbB) { Encb = (unsigned short*)((char*)d_ws + off); off += encbB; }
    if (Encb && ws_size >= off + xbfB)   { Xb   = (unsigned short*)((char*)d_ws + off); off += xbfB; }

    if (decTb) sae_conv_decT<<<dim3(M_DIM / 64, H_DIM / 64), 256, 0, stream>>>(dec, decTb);
    if (Encb)  sae_conv_enc<<<(M_DIM * H_DIM) / 2048, 256, 0, stream>>>(enc, Encb);
    if (Xb)    sae_conv_x<<<(int)(((size_t)N * H_DIM) / 2048), 256, 0, stream>>>(zL, bpre, Xb);

    if (Xb) {
        sae_encode_gemm64<<<(M_DIM / 128) * (N / 128), 256, 0, stream>>>(Xb, Encb, benc, zOut);
    } else {
        dim3 eg(M_DIM / 128, N / 128);
        if (Encb) sae_encode_gemm<1><<<eg, 256, 0, stream>>>(zL, enc, Encb, bpre, benc, zOut);
        else      sae_encode_gemm<0><<<eg, 256, 0, stream>>>(zL, enc, nullptr, bpre, benc, zOut);
    }

    sae_topk<<<N, 256, 0, stream>>>(zOut, zL, enc, bpre, benc, decTb, xOut, decTb ? 1 : 0);
    if (!decTb) sae_decode_fb<<<N / 4, 256, 0, stream>>>(zOut, dec, bpre, xOut);
}